// Round 8
// baseline (362.527 us; speedup 1.0000x reference)
//
#include <hip/hip_runtime.h>
#include <hip/hip_bf16.h>
#include <cstdint>

#define B_ROWS 16384
#define NCLS 1000
#define NPAD 1024
#define FDIM 768
#define TEMP_INV 10.0f
#define BCAP 128

typedef float floatx4 __attribute__((ext_vector_type(4)));
typedef short short8 __attribute__((ext_vector_type(8)));
typedef unsigned short ushort8v __attribute__((ext_vector_type(8)));

__device__ inline unsigned short f2bf(float f) {
  unsigned int u = __float_as_uint(f);
  u += 0x7FFFu + ((u >> 16) & 1u);   // round-to-nearest-even
  return (unsigned short)(u >> 16);
}

#define GLDS(gp, lp) __builtin_amdgcn_global_load_lds( \
    (const __attribute__((address_space(1))) void*)(gp), \
    (__attribute__((address_space(3))) void*)(lp), 16, 0, 0)

#define CVT_BLOCKS 6528     // (16384*768 + 1024*768)/8/256
#define GEMM_BLOCKS 2048
#define CE_BLOCKS  4096     // 16384/4

// ---------------- cvt: features+centers fp32 -> bf16; block 0 zeroes accumulators
__global__ __launch_bounds__(256) void cvt_kernel(
    const float* __restrict__ features, const float* __restrict__ centers,
    unsigned short* __restrict__ fbf, unsigned short* __restrict__ cbf,
    float* __restrict__ ce_acc, unsigned int* __restrict__ done) {
  if (blockIdx.x == 0) {
    if (threadIdx.x < 512) ce_acc[threadIdx.x] = 0.f;
    if (threadIdx.x == 0) *done = 0u;
  }
  const int NF8 = B_ROWS * FDIM / 8;
  int i = blockIdx.x * 256 + threadIdx.x;
  float4 v0, v1;
  unsigned short* dst;
  if (i < NF8) {
    const float4* s = reinterpret_cast<const float4*>(features) + (size_t)i * 2;
    v0 = s[0]; v1 = s[1];
    dst = fbf + (size_t)i * 8;
  } else {
    int j = i - NF8;
    if (j * 8 < NCLS * FDIM) {
      const float4* s = reinterpret_cast<const float4*>(centers) + (size_t)j * 2;
      v0 = s[0]; v1 = s[1];
    } else {
      v0.x = v0.y = v0.z = v0.w = 0.f;
      v1 = v0;
    }
    dst = cbf + (size_t)j * 8;
  }
  ushort8v o;
  o[0] = f2bf(v0.x); o[1] = f2bf(v0.y); o[2] = f2bf(v0.z); o[3] = f2bf(v0.w);
  o[4] = f2bf(v1.x); o[5] = f2bf(v1.y); o[6] = f2bf(v1.z); o[7] = f2bf(v1.w);
  *reinterpret_cast<ushort8v*>(dst) = o;
}

// ---------------- GEMM + per-colblock softmax partials (round-4 structure,
// measured 41 us alone, 0 bank conflicts).
__global__ __launch_bounds__(256) void gemm_stats_kernel(
    const unsigned short* __restrict__ fbf,
    const unsigned short* __restrict__ cbf,
    const int* __restrict__ labels,
    float* __restrict__ pm, float* __restrict__ psv,
    float* __restrict__ ztrue, int* __restrict__ bcnt) {
  __shared__ __align__(16) unsigned short As[64 * 64];    // 8 KB
  __shared__ __align__(16) unsigned short Bs[128 * 64];   // 16 KB
  __shared__ int lab[64];
  __shared__ float sm[64][2], ss[64][2];

  const int t = threadIdx.x;
  const int bid = blockIdx.x;
  if (t == 0 && bid < NCLS) bcnt[bid] = 0;   // zero bucket counters for combine

  const int rowblk = (bid & 7) + 8 * (bid >> 6);   // 0..255; 8 colblks share an XCD
  const int colblk = (bid >> 3) & 7;               // 0..7
  const int w = t >> 6, lane = t & 63;
  const int quad = lane >> 4, l15 = lane & 15;
  const int wr = w >> 1, wc = w & 1;

  if (t < 64) lab[t] = labels[rowblk * 64 + t];

  // staging: chunk p (16B) -> LDS offset p*16; global piece = (p&7)^(row&7)
  const int tq = t >> 3, tr = t & 7;
  const int gp = tr ^ (tq & 7);
  const unsigned short* agp0 = fbf + (size_t)(rowblk * 64 + 0 * 32 + tq) * FDIM + gp * 8;
  const unsigned short* agp1 = fbf + (size_t)(rowblk * 64 + 1 * 32 + tq) * FDIM + gp * 8;
  const unsigned short* bgp0 = cbf + (size_t)(colblk * 128 + 0 * 32 + tq) * FDIM + gp * 8;
  const unsigned short* bgp1 = cbf + (size_t)(colblk * 128 + 1 * 32 + tq) * FDIM + gp * 8;
  const unsigned short* bgp2 = cbf + (size_t)(colblk * 128 + 2 * 32 + tq) * FDIM + gp * 8;
  const unsigned short* bgp3 = cbf + (size_t)(colblk * 128 + 3 * 32 + tq) * FDIM + gp * 8;
  unsigned short* al0 = &As[(0 * 256 + w * 64) * 8];
  unsigned short* al1 = &As[(1 * 256 + w * 64) * 8];
  unsigned short* bl0 = &Bs[(0 * 256 + w * 64) * 8];
  unsigned short* bl1 = &Bs[(1 * 256 + w * 64) * 8];
  unsigned short* bl2 = &Bs[(2 * 256 + w * 64) * 8];
  unsigned short* bl3 = &Bs[(3 * 256 + w * 64) * 8];

  const int swz = l15 & 7;

  floatx4 acc[2][4];
#pragma unroll
  for (int i = 0; i < 2; ++i)
#pragma unroll
    for (int j = 0; j < 4; ++j) acc[i][j] = (floatx4){0.f, 0.f, 0.f, 0.f};

#pragma unroll
  for (int kk = 0; kk < 12; ++kk) {
    __syncthreads();                       // prev tile fully consumed
    const int ko = kk * 64;
    GLDS(agp0 + ko, al0);
    GLDS(agp1 + ko, al1);
    GLDS(bgp0 + ko, bl0);
    GLDS(bgp1 + ko, bl1);
    GLDS(bgp2 + ko, bl2);
    GLDS(bgp3 + ko, bl3);
    __syncthreads();                       // tile resident
    short8 a[2][2], b[4][2];
#pragma unroll
    for (int ks = 0; ks < 2; ++ks) {
      const int qs = ((ks * 4 + quad) ^ swz) * 8;
#pragma unroll
      for (int rb = 0; rb < 2; ++rb)
        a[rb][ks] = *reinterpret_cast<const short8*>(&As[(wr * 32 + rb * 16 + l15) * 64 + qs]);
#pragma unroll
      for (int cb = 0; cb < 4; ++cb)
        b[cb][ks] = *reinterpret_cast<const short8*>(&Bs[(wc * 64 + cb * 16 + l15) * 64 + qs]);
    }
#pragma unroll
    for (int ks = 0; ks < 2; ++ks)
#pragma unroll
      for (int rb = 0; rb < 2; ++rb)
#pragma unroll
        for (int cb = 0; cb < 4; ++cb)
          acc[rb][cb] = __builtin_amdgcn_mfma_f32_16x16x32_bf16(a[rb][ks], b[cb][ks], acc[rb][cb], 0, 0, 0);
  }

  // epilogue: z = 10*sims; per-row partial max/sumexp over this block's 128 cols
  const int gcol0 = colblk * 128 + wc * 64;
#pragma unroll
  for (int rb = 0; rb < 2; ++rb) {
#pragma unroll
    for (int r = 0; r < 4; ++r) {
      const int lrow = wr * 32 + rb * 16 + quad * 4 + r;
      float zv[4];
      float m = -1e30f;
#pragma unroll
      for (int cb = 0; cb < 4; ++cb) {
        float z = acc[rb][cb][r] * TEMP_INV;
        int gc = gcol0 + cb * 16 + l15;
        if (gc == lab[lrow]) ztrue[rowblk * 64 + lrow] = z;
        if (gc >= NCLS) z = -1e30f;
        zv[cb] = z;
        m = fmaxf(m, z);
      }
#pragma unroll
      for (int msk = 1; msk < 16; msk <<= 1) m = fmaxf(m, __shfl_xor(m, msk));
      float s = 0.f;
#pragma unroll
      for (int cb = 0; cb < 4; ++cb) s += __expf(zv[cb] - m);
#pragma unroll
      for (int msk = 1; msk < 16; msk <<= 1) s += __shfl_xor(s, msk);
      if (l15 == 0) { sm[lrow][wc] = m; ss[lrow][wc] = s; }
    }
  }
  __syncthreads();
  if (t < 64) {
    float m0 = sm[t][0], m1 = sm[t][1];
    float mn = fmaxf(m0, m1);
    float S = ss[t][0] * __expf(m0 - mn) + ss[t][1] * __expf(m1 - mn);
    int grow = rowblk * 64 + t;
    pm[colblk * B_ROWS + grow] = mn;
    psv[colblk * B_ROWS + grow] = S;
  }
}

// ---------------- combine: merge partials -> p, SDC partials, class buckets
__global__ __launch_bounds__(256) void combine_kernel(
    const float* __restrict__ pm, const float* __restrict__ psv,
    const float* __restrict__ ztrue, const int* __restrict__ labels,
    int* __restrict__ bcnt, int* __restrict__ bidx, float* __restrict__ bp,
    float* __restrict__ sdc_partial) {
  __shared__ float wred[4];
  const int b = blockIdx.x * 256 + threadIdx.x;
  float mj[8];
  float M = -1e30f;
#pragma unroll
  for (int j = 0; j < 8; ++j) { mj[j] = pm[j * B_ROWS + b]; M = fmaxf(M, mj[j]); }
  float S = 0.f;
#pragma unroll
  for (int j = 0; j < 8; ++j) S += psv[j * B_ROWS + b] * __expf(mj[j] - M);
  float p = __expf(ztrue[b] - M) / S;
  int lb = labels[b];
  int slot = atomicAdd(&bcnt[lb], 1);
  if (slot < BCAP) { bidx[lb * BCAP + slot] = b; bp[lb * BCAP + slot] = p; }
  float v = -logf(p + 1e-8f);
#pragma unroll
  for (int msk = 1; msk < 64; msk <<= 1) v += __shfl_xor(v, msk);
  if ((threadIdx.x & 63) == 0) wred[threadIdx.x >> 6] = v;
  __syncthreads();
  if (threadIdx.x == 0)
    sdc_partial[blockIdx.x] = wred[0] + wred[1] + wred[2] + wred[3];
}

// ---------------- mstep (blocks 0..999) + CE (blocks 1000..5095), fused.
// mstep: latency-bound bucket gather, low BW; CE: pure HBM streaming — they
// overlap on the same CUs. Loss finalized by the LAST CE block via a
// device-scope done-counter (atomics only; no plain-write cross-XCD reads).
__global__ __launch_bounds__(256) void mstep_ce_kernel(
    const float* __restrict__ features,
    const float* __restrict__ centers,
    const int* __restrict__ bcnt, const int* __restrict__ bidx,
    const float* __restrict__ bp,
    const float* __restrict__ outputs, const int* __restrict__ labels,
    const float* __restrict__ sdc_partial,
    float* __restrict__ ce_acc, unsigned int* __restrict__ done,
    float* __restrict__ out_loss, float* __restrict__ out_centers) {
  const int t = threadIdx.x;
  const int bid = blockIdx.x;

  if (bid >= NCLS) {
    // ---- CE path: one wave per row, 4 rows/block
    __shared__ float ared[4];
    const int cb = bid - NCLS;               // 0..4095
    const int wid = t >> 6;
    const int lane = t & 63;
    const int b = cb * 4 + wid;
    const float* row = outputs + (size_t)b * NCLS;
    const float4* r4 = reinterpret_cast<const float4*>(row);
    float4 v[4];
    float m = -1e30f;
#pragma unroll
    for (int it = 0; it < 4; ++it) {
      int idx = lane + it * 64;
      if (idx < 250) v[it] = r4[idx];
      else { v[it].x = -1e30f; v[it].y = -1e30f; v[it].z = -1e30f; v[it].w = -1e30f; }
      m = fmaxf(m, fmaxf(fmaxf(v[it].x, v[it].y), fmaxf(v[it].z, v[it].w)));
    }
#pragma unroll
    for (int msk = 1; msk < 64; msk <<= 1) m = fmaxf(m, __shfl_xor(m, msk));
    float s = 0.f;
#pragma unroll
    for (int it = 0; it < 4; ++it)
      s += __expf(v[it].x - m) + __expf(v[it].y - m) + __expf(v[it].z - m) + __expf(v[it].w - m);
#pragma unroll
    for (int msk = 1; msk < 64; msk <<= 1) s += __shfl_xor(s, msk);
    if (lane == 0) {
      float lse = m + logf(s);
      ared[wid] = lse - row[labels[b]];
    }
    __syncthreads();
    if (t == 0) {
      float bsum = ared[0] + ared[1] + ared[2] + ared[3];
      atomicAdd(&ce_acc[(cb & 31) << 4], bsum);   // 32 slots, 64B-padded
      __threadfence();
      unsigned int old = atomicAdd(done, 1u);
      if (old == CE_BLOCKS - 1) {
        // all CE contributions published (atomic); sdc from prev dispatch
        float ce = 0.f;
#pragma unroll
        for (int k = 0; k < 32; ++k) ce += atomicAdd(&ce_acc[k << 4], 0.f);
        float sd = 0.f;
        for (int i = 0; i < 64; ++i) sd += sdc_partial[i];
        out_loss[0] = (ce + 0.1f * sd) * (1.0f / 16384.0f);
      }
    }
    return;
  }

  // ---- mstep path: one block per class, direct bucket gather
  const int c = bid;
  int n = bcnt[c];
  if (n > BCAP) n = BCAP;
  float a0 = 0.f, a1 = 0.f, a2 = 0.f, ws = 0.f;
  int j = 0;
  for (; j + 2 <= n; j += 2) {
    int b0 = bidx[c * BCAP + j], b1 = bidx[c * BCAP + j + 1];
    float p0 = bp[c * BCAP + j], p1 = bp[c * BCAP + j + 1];
    const float* f0 = features + (size_t)b0 * FDIM;
    const float* f1 = features + (size_t)b1 * FDIM;
    float x00 = f0[t], x01 = f0[t + 256], x02 = f0[t + 512];
    float x10 = f1[t], x11 = f1[t + 256], x12 = f1[t + 512];
    a0 += p0 * x00 + p1 * x10;
    a1 += p0 * x01 + p1 * x11;
    a2 += p0 * x02 + p1 * x12;
    ws += p0 + p1;
  }
  if (j < n) {
    int b0 = bidx[c * BCAP + j];
    float p0 = bp[c * BCAP + j];
    const float* f0 = features + (size_t)b0 * FDIM;
    a0 += p0 * f0[t]; a1 += p0 * f0[t + 256]; a2 += p0 * f0[t + 512];
    ws += p0;
  }
  const float* crow = centers + (size_t)c * FDIM;
  float c0 = crow[t], c1 = crow[t + 256], c2 = crow[t + 512];
  size_t o = (size_t)c * FDIM + t;
  if (ws > 0.f) {
    float inv = 0.1f / (ws + 1e-8f);
    out_centers[o]       = 0.9f * c0 + a0 * inv;
    out_centers[o + 256] = 0.9f * c1 + a1 * inv;
    out_centers[o + 512] = 0.9f * c2 + a2 * inv;
  } else {
    out_centers[o]       = c0;
    out_centers[o + 256] = c1;
    out_centers[o + 512] = c2;
  }
}

extern "C" void kernel_launch(void* const* d_in, const int* in_sizes, int n_in,
                              void* d_out, int out_size, void* d_ws, size_t ws_size,
                              hipStream_t stream) {
  const float* outputs  = (const float*)d_in[0];
  const int*   labels   = (const int*)d_in[1];
  const float* features = (const float*)d_in[2];
  const float* centers  = (const float*)d_in[3];
  float* out = (float*)d_out;

  char* ws = (char*)d_ws;
  float* ztrue       = (float*)(ws);                          // 64 KB
  float* ce_acc      = (float*)(ws + (64 << 10));             // 2 KB (32 slots x 64B)
  unsigned int* done = (unsigned int*)(ws + (66 << 10));      // 4 B
  float* sdc_partial = (float*)(ws + (80 << 10));             // 256 B
  int*   bcnt        = (int*)(ws + (84 << 10));               // 4 KB
  float* pm          = (float*)(ws + (88 << 10));             // 512 KB
  float* psv         = (float*)(ws + (600 << 10));            // 512 KB
  unsigned short* cbf = (unsigned short*)(ws + (1112 << 10)); // 1.5 MB
  unsigned short* fbf = (unsigned short*)(ws + (2648 << 10)); // 24 MB
  // buckets overlay fbf (dead after gemm; written in combine, read in mstep)
  int*   bidx        = (int*)(ws + (2648 << 10));             // 512 KB
  float* bp          = (float*)(ws + (3160 << 10));           // 512 KB

  cvt_kernel<<<CVT_BLOCKS, 256, 0, stream>>>(features, centers, fbf, cbf,
                                             ce_acc, done);
  gemm_stats_kernel<<<GEMM_BLOCKS, 256, 0, stream>>>(
      fbf, cbf, labels, pm, psv, ztrue, bcnt);
  combine_kernel<<<B_ROWS / 256, 256, 0, stream>>>(pm, psv, ztrue, labels,
                                                   bcnt, bidx, bp, sdc_partial);
  mstep_ce_kernel<<<NCLS + CE_BLOCKS, 256, 0, stream>>>(
      features, centers, bcnt, bidx, bp, outputs, labels, sdc_partial,
      ce_acc, done, out, out + 1);
}

// Round 9
// 184.858 us; speedup vs baseline: 1.9611x; 1.9611x over previous
//
#include <hip/hip_runtime.h>
#include <hip/hip_bf16.h>
#include <cstdint>

#define B_ROWS 16384
#define NCLS 1000
#define NPAD 1024
#define FDIM 768
#define TEMP_INV 10.0f
#define BCAP 128

typedef float floatx4 __attribute__((ext_vector_type(4)));
typedef short short8 __attribute__((ext_vector_type(8)));
typedef unsigned short ushort8v __attribute__((ext_vector_type(8)));

__device__ inline unsigned short f2bf(float f) {
  unsigned int u = __float_as_uint(f);
  u += 0x7FFFu + ((u >> 16) & 1u);   // round-to-nearest-even
  return (unsigned short)(u >> 16);
}

#define GLDS(gp, lp) __builtin_amdgcn_global_load_lds( \
    (const __attribute__((address_space(1))) void*)(gp), \
    (__attribute__((address_space(3))) void*)(lp), 16, 0, 0)

#define CVT_BLOCKS 6528     // (16384*768 + 1024*768)/8/256
#define GEMM_BLOCKS 1024    // 128 rowblks x 8 colblks (128x128 tiles)
#define CE_BLOCKS  4096     // 16384/4

// ---------------- cvt: features+centers fp32 -> bf16 (centers zero-padded)
__global__ __launch_bounds__(256) void cvt_kernel(
    const float* __restrict__ features, const float* __restrict__ centers,
    unsigned short* __restrict__ fbf, unsigned short* __restrict__ cbf) {
  const int NF8 = B_ROWS * FDIM / 8;
  int i = blockIdx.x * 256 + threadIdx.x;
  float4 v0, v1;
  unsigned short* dst;
  if (i < NF8) {
    const float4* s = reinterpret_cast<const float4*>(features) + (size_t)i * 2;
    v0 = s[0]; v1 = s[1];
    dst = fbf + (size_t)i * 8;
  } else {
    int j = i - NF8;
    if (j * 8 < NCLS * FDIM) {
      const float4* s = reinterpret_cast<const float4*>(centers) + (size_t)j * 2;
      v0 = s[0]; v1 = s[1];
    } else {
      v0.x = v0.y = v0.z = v0.w = 0.f;
      v1 = v0;
    }
    dst = cbf + (size_t)j * 8;
  }
  ushort8v o;
  o[0] = f2bf(v0.x); o[1] = f2bf(v0.y); o[2] = f2bf(v0.z); o[3] = f2bf(v0.w);
  o[4] = f2bf(v1.x); o[5] = f2bf(v1.y); o[6] = f2bf(v1.z); o[7] = f2bf(v1.w);
  *reinterpret_cast<ushort8v*>(dst) = o;
}

// ---------------- GEMM 128x128 BK=64 (+tail CE blocks) + softmax partials.
// Blocks 0..1023: gemm tile 128x128, 4 waves x (4x4 frags of 16x16x32),
// 12 k-iters, XOR-swizzled LDS (conflict-free, GLDS-legal, coalesced).
// Blocks 1024..5119: CE rows (R6-measured path, no fences/atomics).
__global__ __launch_bounds__(256) void gemm_stats_kernel(
    const unsigned short* __restrict__ fbf,
    const unsigned short* __restrict__ cbf,
    const int* __restrict__ labels,
    const float* __restrict__ outputs,
    float* __restrict__ ce_partial,
    float* __restrict__ pm, float* __restrict__ psv,
    float* __restrict__ ztrue, int* __restrict__ bcnt) {
  __shared__ __align__(16) unsigned short As[128 * 64];   // 16 KB
  __shared__ __align__(16) unsigned short Bs[128 * 64];   // 16 KB
  __shared__ int lab[128];
  __shared__ float sm[128][2], ss[128][2];
  __shared__ float ared[4];

  const int t = threadIdx.x;
  const int bid = blockIdx.x;

  if (bid >= GEMM_BLOCKS) {
    // ---- CE path: one wave per row, 4 rows/block (R6-measured)
    const int cb = bid - GEMM_BLOCKS;        // 0..4095
    const int wid = t >> 6;
    const int lane = t & 63;
    const int b = cb * 4 + wid;
    const float* row = outputs + (size_t)b * NCLS;
    const float4* r4 = reinterpret_cast<const float4*>(row);
    float4 v[4];
    float m = -1e30f;
#pragma unroll
    for (int it = 0; it < 4; ++it) {
      int idx = lane + it * 64;
      if (idx < 250) v[it] = r4[idx];
      else { v[it].x = -1e30f; v[it].y = -1e30f; v[it].z = -1e30f; v[it].w = -1e30f; }
      m = fmaxf(m, fmaxf(fmaxf(v[it].x, v[it].y), fmaxf(v[it].z, v[it].w)));
    }
#pragma unroll
    for (int msk = 1; msk < 64; msk <<= 1) m = fmaxf(m, __shfl_xor(m, msk));
    float s = 0.f;
#pragma unroll
    for (int it = 0; it < 4; ++it)
      s += __expf(v[it].x - m) + __expf(v[it].y - m) + __expf(v[it].z - m) + __expf(v[it].w - m);
#pragma unroll
    for (int msk = 1; msk < 64; msk <<= 1) s += __shfl_xor(s, msk);
    if (lane == 0) {
      float lse = m + logf(s);
      ared[wid] = lse - row[labels[b]];
    }
    __syncthreads();
    if (t == 0)
      ce_partial[cb] = ared[0] + ared[1] + ared[2] + ared[3];
    return;
  }

  // ---- GEMM path
  if (t == 0 && bid < NCLS) bcnt[bid] = 0;   // zero bucket counters for combine

  const int rowblk = (bid & 7) + 8 * (bid >> 6);   // 0..127; 8 colblks share an XCD
  const int colblk = (bid >> 3) & 7;               // 0..7
  const int w = t >> 6, lane = t & 63;
  const int quad = lane >> 4, l15 = lane & 15;
  const int wr = w >> 1, wc = w & 1;

  if (t < 128) lab[t] = labels[rowblk * 128 + t];

  // staging: chunk c = i*256 + t (i=0..3); row = c>>3, lds piece = c&7,
  // global piece = (c&7)^(row&7). LDS contiguous in c (GLDS wave-uniform base).
  const int tq = t >> 3, tr = t & 7;
  const int gp = tr ^ (tq & 7);
  const unsigned short* agp[4];
  const unsigned short* bgp[4];
#pragma unroll
  for (int i = 0; i < 4; ++i) {
    agp[i] = fbf + (size_t)(rowblk * 128 + i * 32 + tq) * FDIM + gp * 8;
    bgp[i] = cbf + (size_t)(colblk * 128 + i * 32 + tq) * FDIM + gp * 8;
  }
  unsigned short* al[4];
  unsigned short* bl[4];
#pragma unroll
  for (int i = 0; i < 4; ++i) {
    al[i] = &As[(i * 256 + w * 64) * 8];
    bl[i] = &Bs[(i * 256 + w * 64) * 8];
  }

  const int swz = l15 & 7;

  floatx4 acc[4][4];
#pragma unroll
  for (int i = 0; i < 4; ++i)
#pragma unroll
    for (int j = 0; j < 4; ++j) acc[i][j] = (floatx4){0.f, 0.f, 0.f, 0.f};

#pragma unroll
  for (int kk = 0; kk < 12; ++kk) {
    __syncthreads();                       // prev tile fully consumed
    const int ko = kk * 64;
#pragma unroll
    for (int i = 0; i < 4; ++i) {
      GLDS(agp[i] + ko, al[i]);
      GLDS(bgp[i] + ko, bl[i]);
    }
    __syncthreads();                       // tile resident
#pragma unroll
    for (int ks = 0; ks < 2; ++ks) {
      const int qs = ((ks * 4 + quad) ^ swz) * 8;
      short8 a[4], b[4];
#pragma unroll
      for (int rb = 0; rb < 4; ++rb)
        a[rb] = *reinterpret_cast<const short8*>(&As[(wr * 64 + rb * 16 + l15) * 64 + qs]);
#pragma unroll
      for (int cb = 0; cb < 4; ++cb)
        b[cb] = *reinterpret_cast<const short8*>(&Bs[(wc * 64 + cb * 16 + l15) * 64 + qs]);
#pragma unroll
      for (int rb = 0; rb < 4; ++rb)
#pragma unroll
        for (int cb = 0; cb < 4; ++cb)
          acc[rb][cb] = __builtin_amdgcn_mfma_f32_16x16x32_bf16(a[rb], b[cb], acc[rb][cb], 0, 0, 0);
    }
  }

  // epilogue: z = 10*sims; per-row partial max/sumexp over this block's 128 cols
  const int gcol0 = colblk * 128 + wc * 64;
#pragma unroll
  for (int rb = 0; rb < 4; ++rb) {
#pragma unroll
    for (int r = 0; r < 4; ++r) {
      const int lrow = wr * 64 + rb * 16 + quad * 4 + r;
      float zv[4];
      float m = -1e30f;
#pragma unroll
      for (int cb = 0; cb < 4; ++cb) {
        float z = acc[rb][cb][r] * TEMP_INV;
        int gc = gcol0 + cb * 16 + l15;
        if (gc == lab[lrow]) ztrue[rowblk * 128 + lrow] = z;
        if (gc >= NCLS) z = -1e30f;
        zv[cb] = z;
        m = fmaxf(m, z);
      }
#pragma unroll
      for (int msk = 1; msk < 16; msk <<= 1) m = fmaxf(m, __shfl_xor(m, msk));
      float s = 0.f;
#pragma unroll
      for (int cb = 0; cb < 4; ++cb) s += __expf(zv[cb] - m);
#pragma unroll
      for (int msk = 1; msk < 16; msk <<= 1) s += __shfl_xor(s, msk);
      if (l15 == 0) { sm[lrow][wc] = m; ss[lrow][wc] = s; }
    }
  }
  __syncthreads();
  if (t < 128) {
    float m0 = sm[t][0], m1 = sm[t][1];
    float mn = fmaxf(m0, m1);
    float S = ss[t][0] * __expf(m0 - mn) + ss[t][1] * __expf(m1 - mn);
    int grow = rowblk * 128 + t;
    pm[colblk * B_ROWS + grow] = mn;
    psv[colblk * B_ROWS + grow] = S;
  }
}

// ---------------- combine: merge partials -> p, SDC partials, class buckets
__global__ __launch_bounds__(256) void combine_kernel(
    const float* __restrict__ pm, const float* __restrict__ psv,
    const float* __restrict__ ztrue, const int* __restrict__ labels,
    int* __restrict__ bcnt, int* __restrict__ bidx, float* __restrict__ bp,
    float* __restrict__ sdc_partial) {
  __shared__ float wred[4];
  const int b = blockIdx.x * 256 + threadIdx.x;
  float mj[8];
  float M = -1e30f;
#pragma unroll
  for (int j = 0; j < 8; ++j) { mj[j] = pm[j * B_ROWS + b]; M = fmaxf(M, mj[j]); }
  float S = 0.f;
#pragma unroll
  for (int j = 0; j < 8; ++j) S += psv[j * B_ROWS + b] * __expf(mj[j] - M);
  float p = __expf(ztrue[b] - M) / S;
  int lb = labels[b];
  int slot = atomicAdd(&bcnt[lb], 1);
  if (slot < BCAP) { bidx[lb * BCAP + slot] = b; bp[lb * BCAP + slot] = p; }
  float v = -logf(p + 1e-8f);
#pragma unroll
  for (int msk = 1; msk < 64; msk <<= 1) v += __shfl_xor(v, msk);
  if ((threadIdx.x & 63) == 0) wred[threadIdx.x >> 6] = v;
  __syncthreads();
  if (threadIdx.x == 0)
    sdc_partial[blockIdx.x] = wred[0] + wred[1] + wred[2] + wred[3];
}

// ---------------- mstep: one block per class, direct bucket gather.
// Block 0 additionally finalizes the scalar loss (no fences — R7-proven).
__global__ __launch_bounds__(256) void mstep_kernel(
    const float* __restrict__ features,
    const float* __restrict__ centers,
    const int* __restrict__ bcnt, const int* __restrict__ bidx,
    const float* __restrict__ bp,
    const float* __restrict__ ce_partial, const float* __restrict__ sdc_partial,
    float* __restrict__ out_loss, float* __restrict__ out_centers) {
  const int c = blockIdx.x;
  const int t = threadIdx.x;
  if (c == 0) {
    __shared__ float red[256];
    float s = 0.f;
    for (int i = t; i < CE_BLOCKS; i += 256) s += ce_partial[i];
    float s2 = 0.f;
    for (int i = t; i < 64; i += 256) s2 += sdc_partial[i];
    red[t] = s + 0.1f * s2;
    __syncthreads();
    for (int off = 128; off > 0; off >>= 1) {
      if (t < off) red[t] += red[t + off];
      __syncthreads();
    }
    if (t == 0) out_loss[0] = red[0] * (1.0f / 16384.0f);
  }
  int n = bcnt[c];
  if (n > BCAP) n = BCAP;
  float a0 = 0.f, a1 = 0.f, a2 = 0.f, ws = 0.f;
  int j = 0;
  for (; j + 2 <= n; j += 2) {
    int b0 = bidx[c * BCAP + j], b1 = bidx[c * BCAP + j + 1];
    float p0 = bp[c * BCAP + j], p1 = bp[c * BCAP + j + 1];
    const float* f0 = features + (size_t)b0 * FDIM;
    const float* f1 = features + (size_t)b1 * FDIM;
    float x00 = f0[t], x01 = f0[t + 256], x02 = f0[t + 512];
    float x10 = f1[t], x11 = f1[t + 256], x12 = f1[t + 512];
    a0 += p0 * x00 + p1 * x10;
    a1 += p0 * x01 + p1 * x11;
    a2 += p0 * x02 + p1 * x12;
    ws += p0 + p1;
  }
  if (j < n) {
    int b0 = bidx[c * BCAP + j];
    float p0 = bp[c * BCAP + j];
    const float* f0 = features + (size_t)b0 * FDIM;
    a0 += p0 * f0[t]; a1 += p0 * f0[t + 256]; a2 += p0 * f0[t + 512];
    ws += p0;
  }
  const float* crow = centers + (size_t)c * FDIM;
  float c0 = crow[t], c1 = crow[t + 256], c2 = crow[t + 512];
  size_t o = (size_t)c * FDIM + t;
  if (ws > 0.f) {
    float inv = 0.1f / (ws + 1e-8f);
    out_centers[o]       = 0.9f * c0 + a0 * inv;
    out_centers[o + 256] = 0.9f * c1 + a1 * inv;
    out_centers[o + 512] = 0.9f * c2 + a2 * inv;
  } else {
    out_centers[o]       = c0;
    out_centers[o + 256] = c1;
    out_centers[o + 512] = c2;
  }
}

extern "C" void kernel_launch(void* const* d_in, const int* in_sizes, int n_in,
                              void* d_out, int out_size, void* d_ws, size_t ws_size,
                              hipStream_t stream) {
  const float* outputs  = (const float*)d_in[0];
  const int*   labels   = (const int*)d_in[1];
  const float* features = (const float*)d_in[2];
  const float* centers  = (const float*)d_in[3];
  float* out = (float*)d_out;

  char* ws = (char*)d_ws;
  float* ztrue       = (float*)(ws);                          // 64 KB
  float* ce_partial  = (float*)(ws + (64 << 10));             // 16 KB
  float* sdc_partial = (float*)(ws + (80 << 10));             // 256 B
  int*   bcnt        = (int*)(ws + (84 << 10));               // 4 KB
  float* pm          = (float*)(ws + (88 << 10));             // 512 KB
  float* psv         = (float*)(ws + (600 << 10));            // 512 KB
  unsigned short* cbf = (unsigned short*)(ws + (1112 << 10)); // 1.5 MB
  unsigned short* fbf = (unsigned short*)(ws + (2648 << 10)); // 24 MB
  // buckets overlay fbf (dead after gemm; written in combine, read in mstep)
  int*   bidx        = (int*)(ws + (2648 << 10));             // 512 KB
  float* bp          = (float*)(ws + (3160 << 10));           // 512 KB

  cvt_kernel<<<CVT_BLOCKS, 256, 0, stream>>>(features, centers, fbf, cbf);
  gemm_stats_kernel<<<GEMM_BLOCKS + CE_BLOCKS, 256, 0, stream>>>(
      fbf, cbf, labels, outputs, ce_partial, pm, psv, ztrue, bcnt);
  combine_kernel<<<B_ROWS / 256, 256, 0, stream>>>(pm, psv, ztrue, labels,
                                                   bcnt, bidx, bp, sdc_partial);
  mstep_kernel<<<NCLS, 256, 0, stream>>>(features, centers, bcnt, bidx, bp,
                                         ce_partial, sdc_partial, out, out + 1);
}